// Round 9
// baseline (82.641 us; speedup 1.0000x reference)
//
#include <hip/hip_runtime.h>

#define PCX 512.0f
#define PCY 512.0f

typedef float f32x2 __attribute__((ext_vector_type(2)));
typedef float f32x4 __attribute__((ext_vector_type(4)));

// ---------------------------------------------------------------------------
// Single fused kernel: one block = one view x 512-point chunk.
// A/B vs round 8: ONLY change is nontemporal stores -> plain cached stores.
// grid.x padded to %8 so chunk->XCD mapping is view-invariant.
// Blocks retire in dispatch order -> store stream sweeps memory
// near-sequentially. Camera composed redundantly per-thread (wave-uniform,
// hidden under the memory stream; verified neutral R6->R7).
//   m[0..2] = -f*row0, c0 = -f*tx   ->  u = (m.P + c0)*(1/Z) + CX
//   m[3..5] =  f*row1, c1 =  f*ty   ->  v = (m.P + c1)*(1/Z) + CY
//   m[6..8] =    row2, c2 =     tz  ->  Z =  m.P + c2
// ---------------------------------------------------------------------------
__global__ void __launch_bounds__(256)
proj_kernel(const f32x2* __restrict__ pts2,
            const float* __restrict__ eulers,
            const float* __restrict__ trans,
            const float* __restrict__ focal_p,
            float* __restrict__ out,
            int N, int Npairs, long long VN) {
    const int v = blockIdx.y;

    // ---- per-view camera, computed redundantly in every thread ----
    const float f = *focal_p;
    const float a = eulers[3 * v + 0], b = eulers[3 * v + 1], c = eulers[3 * v + 2];
    float sa, ca, sb, cb, sc, cc;
    sincosf(a, &sa, &ca);
    sincosf(b, &sb, &cb);
    sincosf(c, &sc, &cc);
    const float r00 = cb * cc,                 r01 = -cb * sc,                r02 = sb;
    const float r10 = ca * sc + sa * sb * cc,  r11 = ca * cc - sa * sb * sc,  r12 = -sa * cb;
    const float r20 = sa * sc - ca * sb * cc,  r21 = sa * cc + ca * sb * sc,  r22 = ca * cb;
    const float m0 = -f * r00, m1 = -f * r01, m2 = -f * r02;
    const float m3 =  f * r10, m4 =  f * r11, m5 =  f * r12;
    const float m6 =  r20,     m7 =  r21,     m8 =  r22;
    const float c0 = -f * trans[3 * v + 0];
    const float c1 =  f * trans[3 * v + 1];
    const float c2 =  trans[3 * v + 2];

    const int t = blockIdx.x * blockDim.x + threadIdx.x;
    if (t >= Npairs) return;   // also culls the grid-pad blocks

    const bool hasP1 = (2 * t + 1 < N);
    // load 2 points = 6 floats as 3x float2 (24B contiguous per thread)
    const f32x2 A = pts2[3 * t + 0];
    const f32x2 B = hasP1 ? pts2[3 * t + 1] : f32x2{0.f, 0.f};
    const f32x2 C = hasP1 ? pts2[3 * t + 2] : f32x2{pts2[3 * t + 1].x, 0.f};
    const float x0 = A.x, y0 = A.y;
    const float z0 = hasP1 ? B.x : C.x;
    const float x1 = B.y, y1 = C.x, z1 = C.y;

    const float X0 = fmaf(m0, x0, fmaf(m1, y0, fmaf(m2, z0, c0)));
    const float Y0 = fmaf(m3, x0, fmaf(m4, y0, fmaf(m5, z0, c1)));
    const float Z0 = fmaf(m6, x0, fmaf(m7, y0, fmaf(m8, z0, c2)));
    const float r0 = __builtin_amdgcn_rcpf(Z0);
    const float u0 = fmaf(X0, r0, PCX);
    const float w0 = fmaf(Y0, r0, PCY);

    const float X1 = fmaf(m0, x1, fmaf(m1, y1, fmaf(m2, z1, c0)));
    const float Y1 = fmaf(m3, x1, fmaf(m4, y1, fmaf(m5, z1, c1)));
    const float Z1 = fmaf(m6, x1, fmaf(m7, y1, fmaf(m8, z1, c2)));
    const float r1 = __builtin_amdgcn_rcpf(Z1);
    const float u1 = fmaf(X1, r1, PCX);
    const float w1 = fmaf(Y1, r1, PCY);

    if (((N & 1) == 0) && hasP1) {
        f32x4 uvv; uvv.x = u0; uvv.y = w0; uvv.z = u1; uvv.w = w1;
        f32x2 zz;  zz.x = Z0;  zz.y = Z1;
        const int halfN = N >> 1;
        reinterpret_cast<f32x4*>(out)[(long long)v * halfN + t] = uvv;
        reinterpret_cast<f32x2*>(out + 2 * VN)[(long long)v * halfN + t] = zz;
    } else {
        const long long idx = (long long)v * N + 2LL * t;
        out[2 * idx + 0] = u0;
        out[2 * idx + 1] = w0;
        out[2 * VN + idx] = Z0;
        if (hasP1) {
            out[2 * idx + 2] = u1;
            out[2 * idx + 3] = w1;
            out[2 * VN + idx + 1] = Z1;
        }
    }
}

extern "C" void kernel_launch(void* const* d_in, const int* in_sizes, int n_in,
                              void* d_out, int out_size, void* d_ws, size_t ws_size,
                              hipStream_t stream) {
    const float* focal  = (const float*)d_in[0];
    const float* eulers = (const float*)d_in[1];
    const float* trans  = (const float*)d_in[2];
    const float* pts    = (const float*)d_in[3];

    const int V = in_sizes[1] / 3;
    const int N = in_sizes[3] / 3;
    const int Npairs = (N + 1) / 2;
    const long long VN = (long long)V * N;

    float* out = (float*)d_out;

    // pad grid.x to a multiple of 8 so chunk->XCD mapping is view-invariant
    int gx = (Npairs + 255) / 256;
    gx = (gx + 7) & ~7;

    dim3 block(256, 1, 1);
    dim3 grid(gx, V, 1);
    proj_kernel<<<grid, block, 0, stream>>>(
        reinterpret_cast<const f32x2*>(pts), eulers, trans, focal, out,
        N, Npairs, VN);
}

// Round 10
// 66.374 us; speedup vs baseline: 1.2451x; 1.2451x over previous
//
#include <hip/hip_runtime.h>

#define PCX 512.0f
#define PCY 512.0f

typedef float f32x2 __attribute__((ext_vector_type(2)));
typedef float f32x4 __attribute__((ext_vector_type(4)));

// ---------------------------------------------------------------------------
// Fused kernel, VCHUNK=2: one block = 2 views x 512-point chunk.
// vs R8 (71.1us, best): each thread loads its point-pair ONCE and projects
// into TWO views, halving the per-view point re-read traffic (384->192 MB of
// L3 reads) while keeping the flat x-major store sweep and NT stores
// (NT confirmed +11.5us vs cached in R9 A/B).
// grid.x padded to %8 so chunk->XCD mapping is view-invariant.
// Camera composed redundantly per-thread (wave-uniform, hidden; verified
// neutral R6->R7).
//   m[0..2] = -f*row0, c0 = -f*tx   ->  u = (m.P + c0)*(1/Z) + CX
//   m[3..5] =  f*row1, c1 =  f*ty   ->  v = (m.P + c1)*(1/Z) + CY
//   m[6..8] =    row2, c2 =     tz  ->  Z =  m.P + c2
// ---------------------------------------------------------------------------
__global__ void __launch_bounds__(256)
proj_kernel(const f32x2* __restrict__ pts2,
            const float* __restrict__ eulers,
            const float* __restrict__ trans,
            const float* __restrict__ focal_p,
            float* __restrict__ out,
            int N, int Npairs, long long VN, int V) {
    const int t = blockIdx.x * blockDim.x + threadIdx.x;
    if (t >= Npairs) return;   // also culls the grid-pad blocks

    const int v0 = 2 * blockIdx.y;
    const int nvv = min(2, V - v0);
    const float f = *focal_p;

    const bool hasP1 = (2 * t + 1 < N);
    // load 2 points = 6 floats as 3x float2 (24B contiguous per thread)
    const f32x2 A = pts2[3 * t + 0];
    const f32x2 B = hasP1 ? pts2[3 * t + 1] : f32x2{0.f, 0.f};
    const f32x2 C = hasP1 ? pts2[3 * t + 2] : f32x2{pts2[3 * t + 1].x, 0.f};
    const float x0 = A.x, y0 = A.y;
    const float z0 = hasP1 ? B.x : C.x;
    const float x1 = B.y, y1 = C.x, z1 = C.y;

    const bool vec = ((N & 1) == 0) && hasP1;
    const int halfN = N >> 1;

#pragma unroll 2
    for (int dv = 0; dv < 2; ++dv) {
        if (dv >= nvv) break;
        const int v = v0 + dv;

        // ---- per-view camera, computed redundantly in every thread ----
        const float a = eulers[3 * v + 0], b = eulers[3 * v + 1], c = eulers[3 * v + 2];
        float sa, ca, sb, cb, sc, cc;
        sincosf(a, &sa, &ca);
        sincosf(b, &sb, &cb);
        sincosf(c, &sc, &cc);
        const float r00 = cb * cc,                 r01 = -cb * sc,                r02 = sb;
        const float r10 = ca * sc + sa * sb * cc,  r11 = ca * cc - sa * sb * sc,  r12 = -sa * cb;
        const float r20 = sa * sc - ca * sb * cc,  r21 = sa * cc + ca * sb * sc,  r22 = ca * cb;
        const float m0 = -f * r00, m1 = -f * r01, m2 = -f * r02;
        const float m3 =  f * r10, m4 =  f * r11, m5 =  f * r12;
        const float m6 =  r20,     m7 =  r21,     m8 =  r22;
        const float c0 = -f * trans[3 * v + 0];
        const float c1 =  f * trans[3 * v + 1];
        const float c2 =  trans[3 * v + 2];

        const float X0 = fmaf(m0, x0, fmaf(m1, y0, fmaf(m2, z0, c0)));
        const float Y0 = fmaf(m3, x0, fmaf(m4, y0, fmaf(m5, z0, c1)));
        const float Z0 = fmaf(m6, x0, fmaf(m7, y0, fmaf(m8, z0, c2)));
        const float r0 = __builtin_amdgcn_rcpf(Z0);
        const float u0 = fmaf(X0, r0, PCX);
        const float w0 = fmaf(Y0, r0, PCY);

        const float X1 = fmaf(m0, x1, fmaf(m1, y1, fmaf(m2, z1, c0)));
        const float Y1 = fmaf(m3, x1, fmaf(m4, y1, fmaf(m5, z1, c1)));
        const float Z1 = fmaf(m6, x1, fmaf(m7, y1, fmaf(m8, z1, c2)));
        const float r1 = __builtin_amdgcn_rcpf(Z1);
        const float u1 = fmaf(X1, r1, PCX);
        const float w1 = fmaf(Y1, r1, PCY);

        if (vec) {
            f32x4 uvv; uvv.x = u0; uvv.y = w0; uvv.z = u1; uvv.w = w1;
            f32x2 zz;  zz.x = Z0;  zz.y = Z1;
            __builtin_nontemporal_store(uvv,
                reinterpret_cast<f32x4*>(out) + (long long)v * halfN + t);
            __builtin_nontemporal_store(zz,
                reinterpret_cast<f32x2*>(out + 2 * VN) + (long long)v * halfN + t);
        } else {
            const long long idx = (long long)v * N + 2LL * t;
            out[2 * idx + 0] = u0;
            out[2 * idx + 1] = w0;
            out[2 * VN + idx] = Z0;
            if (hasP1) {
                out[2 * idx + 2] = u1;
                out[2 * idx + 3] = w1;
                out[2 * VN + idx + 1] = Z1;
            }
        }
    }
}

extern "C" void kernel_launch(void* const* d_in, const int* in_sizes, int n_in,
                              void* d_out, int out_size, void* d_ws, size_t ws_size,
                              hipStream_t stream) {
    const float* focal  = (const float*)d_in[0];
    const float* eulers = (const float*)d_in[1];
    const float* trans  = (const float*)d_in[2];
    const float* pts    = (const float*)d_in[3];

    const int V = in_sizes[1] / 3;
    const int N = in_sizes[3] / 3;
    const int Npairs = (N + 1) / 2;
    const long long VN = (long long)V * N;

    float* out = (float*)d_out;

    // pad grid.x to a multiple of 8 so chunk->XCD mapping is view-invariant
    int gx = (Npairs + 255) / 256;
    gx = (gx + 7) & ~7;

    dim3 block(256, 1, 1);
    dim3 grid(gx, (V + 1) / 2, 1);
    proj_kernel<<<grid, block, 0, stream>>>(
        reinterpret_cast<const f32x2*>(pts), eulers, trans, focal, out,
        N, Npairs, VN, V);
}